// Round 1
// baseline (873.474 us; speedup 1.0000x reference)
//
#include <hip/hip_runtime.h>

// Problem constants: B=4, Cin=Cout=64, H=W=128, K=9, PAD=1
// Layout: NCHW fp32. HW plane = 16384 elements.

// ---------------- prep: transpose main weights to [c][k][o], BN constants ----
__global__ __launch_bounds__(256) void prep_kernel(
    const float* __restrict__ w1, const float* __restrict__ w2,
    const float* __restrict__ g1, const float* __restrict__ be1,
    const float* __restrict__ m1, const float* __restrict__ v1,
    const float* __restrict__ g2, const float* __restrict__ be2,
    const float* __restrict__ m2, const float* __restrict__ v2,
    float* __restrict__ wt1, float* __restrict__ wt2,
    float* __restrict__ bn1, float* __restrict__ bn2) {
  int idx = blockIdx.x * 256 + threadIdx.x;
  if (idx < 36864) {
    int o = idx & 63, ck = idx >> 6;
    int c = ck / 9, k = ck - c * 9;
    wt1[idx] = w1[(o * 64 + c) * 9 + k];     // w[o][c][k] -> wt[(c*9+k)*64+o]
  } else if (idx < 73728) {
    int i = idx - 36864;
    int o = i & 63, ck = i >> 6;
    int c = ck / 9, k = ck - c * 9;
    wt2[i] = w2[(o * 64 + c) * 9 + k];
  } else if (idx < 73728 + 64) {
    int o = idx - 73728;
    float s = g1[o] * rsqrtf(v1[o] + 1e-5f);
    bn1[o] = s;
    bn1[64 + o] = be1[o] - m1[o] * s;
  } else if (idx < 73728 + 128) {
    int o = idx - 73728 - 64;
    float s = g2[o] * rsqrtf(v2[o] + 1e-5f);
    bn2[o] = s;
    bn2[64 + o] = be2[o] - m2[o] * s;
  }
}

// ---------------- offset conv: 3x3, 64 -> 18 channels, zero pad -------------
// block = 32x8 threads covering a 32x8 output tile; LDS halo tile per channel.
__global__ __launch_bounds__(256) void conv_off_kernel(
    const float* __restrict__ xin, const float* __restrict__ woff,
    const float* __restrict__ boff, float* __restrict__ off) {
  __shared__ float tile[10][34];
  int tx = threadIdx.x, ty = threadIdx.y;
  int bx = blockIdx.x, by = blockIdx.y, b = blockIdx.z;
  int gx = bx * 32 + tx, gy = by * 8 + ty;
  int tid = ty * 32 + tx;

  float a[18];
#pragma unroll
  for (int j = 0; j < 18; ++j) a[j] = boff[j];

  for (int c = 0; c < 64; ++c) {
    __syncthreads();
    const float* xc = xin + ((size_t)(b * 64 + c) << 14);
    for (int i = tid; i < 340; i += 256) {
      int r = i / 34, cc = i - r * 34;
      int yy = by * 8 + r - 1, xx = bx * 32 + cc - 1;
      float v = 0.f;
      if (yy >= 0 && yy < 128 && xx >= 0 && xx < 128) v = xc[(yy << 7) + xx];
      tile[r][cc] = v;
    }
    __syncthreads();
    float v[9];
#pragma unroll
    for (int t = 0; t < 9; ++t) v[t] = tile[ty + t / 3][tx + t % 3];
    const float* wb = woff + c * 9;  // woff[j][c][t] = woff[j*576 + c*9 + t]
#pragma unroll
    for (int j = 0; j < 18; ++j) {
      const float* wj = wb + j * 576;  // uniform -> scalar loads
#pragma unroll
      for (int t = 0; t < 9; ++t) a[j] = fmaf(v[t], wj[t], a[j]);
    }
  }
  int hw = (gy << 7) + gx;
#pragma unroll
  for (int j = 0; j < 18; ++j) off[((b * 18 + j) << 14) + hw] = a[j];
}

// ---------------- fused deformable sample + einsum + BN + ReLU --------------
// 1 thread = 1 pixel, all 64 output channels in registers.
__global__ __launch_bounds__(256) void dcn_main_kernel(
    const float* __restrict__ xin, const float* __restrict__ off,
    const float* __restrict__ wt, const float* __restrict__ bn,
    float* __restrict__ out) {
  int p = blockIdx.x * 256 + threadIdx.x;
  int w = p & 127, h = (p >> 7) & 127, b = p >> 14;
  int hw = (h << 7) + w;

  float acc[64];
#pragma unroll
  for (int o = 0; o < 64; ++o) acc[o] = 0.f;

  const float* xb = xin + ((size_t)b << 20);  // b * 64 * 16384

#pragma unroll 1
  for (int k = 0; k < 9; ++k) {
    float dy = off[((b * 18 + 2 * k) << 14) + hw];
    float dx = off[((b * 18 + 2 * k + 1) << 14) + hw];
    float py = (float)(h + k / 3 - 1) + dy;
    float px = (float)(w + (k % 3) - 1) + dx;
    float y0f = floorf(py), x0f = floorf(px);
    float wy1 = py - y0f, wx1 = px - x0f;
    float wy0 = 1.f - wy1, wx0 = 1.f - wx1;
    int y0 = (int)y0f, x0 = (int)x0f;
    int y1 = y0 + 1, x1 = x0 + 1;
    bool vy0 = (y0 >= 0) && (y0 <= 127);
    bool vy1 = (y1 >= 0) && (y1 <= 127);
    bool vx0 = (x0 >= 0) && (x0 <= 127);
    bool vx1 = (x1 >= 0) && (x1 <= 127);
    float w00 = (vy0 && vx0) ? wy0 * wx0 : 0.f;
    float w01 = (vy0 && vx1) ? wy0 * wx1 : 0.f;
    float w10 = (vy1 && vx0) ? wy1 * wx0 : 0.f;
    float w11 = (vy1 && vx1) ? wy1 * wx1 : 0.f;
    int y0c = min(max(y0, 0), 127), y1c = min(max(y1, 0), 127);
    int x0c = min(max(x0, 0), 127), x1c = min(max(x1, 0), 127);
    int i00 = (y0c << 7) + x0c, i01 = (y0c << 7) + x1c;
    int i10 = (y1c << 7) + x0c, i11 = (y1c << 7) + x1c;

    // software-pipelined taps: load c's taps while c-1's FMAs run
    float t00 = xb[i00], t01 = xb[i01], t10 = xb[i10], t11 = xb[i11];
#pragma unroll 2
    for (int c = 0; c < 64; ++c) {
      float s = fmaf(w00, t00, fmaf(w01, t01, fmaf(w10, t10, w11 * t11)));
      if (c < 63) {
        const float* xn = xb + ((size_t)(c + 1) << 14);
        t00 = xn[i00]; t01 = xn[i01]; t10 = xn[i10]; t11 = xn[i11];
      }
      const float* wp = wt + ((c * 9 + k) << 6);  // uniform -> s_load
#pragma unroll
      for (int o = 0; o < 64; ++o) acc[o] = fmaf(s, wp[o], acc[o]);
    }
  }

#pragma unroll
  for (int o = 0; o < 64; ++o) {
    float r = fmaf(acc[o], bn[o], bn[64 + o]);
    out[((b * 64 + o) << 14) + hw] = fmaxf(r, 0.f);
  }
}

extern "C" void kernel_launch(void* const* d_in, const int* in_sizes, int n_in,
                              void* d_out, int out_size, void* d_ws, size_t ws_size,
                              hipStream_t stream) {
  const float* x      = (const float*)d_in[0];
  const float* w_off1 = (const float*)d_in[1];
  const float* b_off1 = (const float*)d_in[2];
  const float* w1     = (const float*)d_in[3];
  const float* g1     = (const float*)d_in[4];
  const float* be1    = (const float*)d_in[5];
  const float* m1     = (const float*)d_in[6];
  const float* v1     = (const float*)d_in[7];
  const float* w_off2 = (const float*)d_in[8];
  const float* b_off2 = (const float*)d_in[9];
  const float* w2     = (const float*)d_in[10];
  const float* g2     = (const float*)d_in[11];
  const float* be2    = (const float*)d_in[12];
  const float* m2     = (const float*)d_in[13];
  const float* v2     = (const float*)d_in[14];
  float* out = (float*)d_out;

  float* ws   = (float*)d_ws;
  float* wt1  = ws;                       // 36864
  float* wt2  = ws + 36864;               // 36864
  float* bn1  = ws + 73728;               // 128
  float* bn2  = ws + 73856;               // 128
  float* offb = ws + 73984;               // 4*18*16384 = 1179648
  float* hbuf = ws + 73984 + 1179648;     // 4*64*16384 = 4194304

  prep_kernel<<<289, 256, 0, stream>>>(w1, w2, g1, be1, m1, v1, g2, be2, m2, v2,
                                       wt1, wt2, bn1, bn2);

  dim3 cgrid(4, 16, 4), cblk(32, 8);
  conv_off_kernel<<<cgrid, cblk, 0, stream>>>(x, w_off1, b_off1, offb);
  dcn_main_kernel<<<256, 256, 0, stream>>>(x, offb, wt1, bn1, hbuf);

  conv_off_kernel<<<cgrid, cblk, 0, stream>>>(hbuf, w_off2, b_off2, offb);
  dcn_main_kernel<<<256, 256, 0, stream>>>(hbuf, offb, wt2, bn2, out);
}